// Round 1
// baseline (389.945 us; speedup 1.0000x reference)
//
#include <hip/hip_runtime.h>
#include <hip/hip_bf16.h>

#define NN 128   // graph nodes N
#define ND 256   // feature dim D

typedef __attribute__((ext_vector_type(8))) short short8v;
typedef __attribute__((ext_vector_type(4))) short short4v;
typedef __attribute__((ext_vector_type(4))) float floatx4;

__device__ __forceinline__ unsigned short f2bf(float x){
  unsigned u = __float_as_uint(x);
  u += 0x7FFF + ((u >> 16) & 1);   // round-to-nearest-even
  return (unsigned short)(u >> 16);
}
__device__ __forceinline__ float bf2f(unsigned short h){
  return __uint_as_float(((unsigned)h) << 16);
}

// Precompute Abf[256][128] bf16: rows 0..127 = origin*adj_in ; rows 128..255 = origin^T*adj_out
__global__ void prep_A(const float* __restrict__ adj_in, const float* __restrict__ adj_out,
                       unsigned short* __restrict__ Abf){
  int idx = blockIdx.x * 256 + threadIdx.x;   // 0..32767
  int m = idx >> 7, n = idx & 127;
  float v;
  if (m < NN){
    float a = adj_in[m * NN + n];
    v = (a <= 0.f) ? a * a : a;               // origin(a)*a
  } else {
    int mm = m - NN;
    float t = adj_in[n * NN + mm];            // origin^T[mm][n] = f(adj_in[n][mm])
    float o = (t <= 0.f) ? t : 1.f;
    v = o * adj_out[mm * NN + n];
  }
  Abf[idx] = f2bf(v);
}

__global__ __launch_bounds__(512) void gcn_main(
    const float* __restrict__ H, const unsigned short* __restrict__ Abf,
    const float* __restrict__ eb,  const float* __restrict__ gw,
    const float* __restrict__ bg,  const float* __restrict__ oeb,
    const float* __restrict__ ogw, const float* __restrict__ obg,
    const float* __restrict__ lw,  float* __restrict__ Out)
{
  // Ht: bf16, logically [d][n] (transposed H_b), XOR-swizzled in 16B granules:
  // short index = d*128 + (n ^ ((d&7)<<3))
  __shared__ __align__(16) unsigned short Ht[ND * NN];
  __shared__ float sigS[3 * NN];   // [0..127]=sig_in, [128..255]=sig_out, [256..383]=sig_loop

  const int tid  = threadIdx.x;
  const int wave = tid >> 6;
  const int lane = tid & 63;
  const int g    = lane >> 4;
  const int m16  = lane & 15;
  const int b    = blockIdx.x;
  const float* Hb = H   + (size_t)b * NN * ND;
  float*       Ob = Out + (size_t)b * NN * ND;

  // ---- stage H_b -> Ht (bf16, transposed, swizzled) with fused gate dot-products ----
  for (int pi = 0; pi < 2; ++pi){
    int p = 8 * wave + 4 * pi + g;      // node-pair index 0..63 (wave-group uniform)
    int n = 2 * p;
    float s0=0.f,s1=0.f,s2=0.f,s3=0.f,s4=0.f,s5=0.f;
    #pragma unroll
    for (int di = 0; di < 8; ++di){
      int d = 32 * di + 2 * m16;
      float2 a  = *(const float2*)(Hb + n * ND + d);        // row n,   d..d+1
      float2 c  = *(const float2*)(Hb + (n + 1) * ND + d);  // row n+1, d..d+1
      float2 w0 = *(const float2*)(gw  + d);
      float2 w1 = *(const float2*)(ogw + d);
      float2 w2 = *(const float2*)(lw  + d);
      s0 += a.x * w0.x + a.y * w0.y;
      s1 += a.x * w1.x + a.y * w1.y;
      s2 += a.x * w2.x + a.y * w2.y;
      s3 += c.x * w0.x + c.y * w0.y;
      s4 += c.x * w1.x + c.y * w1.y;
      s5 += c.x * w2.x + c.y * w2.y;
      unsigned v0 = (unsigned)f2bf(a.x) | ((unsigned)f2bf(c.x) << 16); // Ht[d  ][n], Ht[d  ][n+1]
      unsigned v1 = (unsigned)f2bf(a.y) | ((unsigned)f2bf(c.y) << 16); // Ht[d+1][n], Ht[d+1][n+1]
      int i0 = d       * NN + (n ^ (( d      & 7) << 3));
      int i1 = (d + 1) * NN + (n ^ (((d + 1) & 7) << 3));
      *(unsigned*)&Ht[i0] = v0;
      *(unsigned*)&Ht[i1] = v1;
    }
    // reduce the 6 gate partials across the 16 lanes of this group (d-coverage is complete)
    #pragma unroll
    for (int m = 1; m < 16; m <<= 1){
      s0 += __shfl_xor(s0, m, 64);
      s1 += __shfl_xor(s1, m, 64);
      s2 += __shfl_xor(s2, m, 64);
      s3 += __shfl_xor(s3, m, 64);
      s4 += __shfl_xor(s4, m, 64);
      s5 += __shfl_xor(s5, m, 64);
    }
    if (m16 == 0){
      float gi0 = s0 + bg[n],     go0 = s1 + obg[n];
      float gi1 = s3 + bg[n + 1], go1 = s4 + obg[n + 1];
      sigS[n]            = 1.f / (1.f + __expf(-gi0));
      sigS[NN + n]       = 1.f / (1.f + __expf(-go0));
      sigS[2 * NN + n]   = 1.f / (1.f + __expf(-s2));
      sigS[n + 1]        = 1.f / (1.f + __expf(-gi1));
      sigS[NN + n + 1]   = 1.f / (1.f + __expf(-go1));
      sigS[2 * NN + n + 1] = 1.f / (1.f + __expf(-s5));
    }
  }
  __syncthreads();

  // ---- GEMM: C[m,d] = sum_n Abf[m,n] * H_b[n,d], m in [0,256) (in-arc rows 0..127, out-arc 128..255)
  const int mrow = 16 * wave + m16;   // this lane's A-row (C1); C2 row = 128 + mrow
  float si_[4], so_[4], sl_[4];
  #pragma unroll
  for (int r = 0; r < 4; ++r){
    int mm = 16 * wave + 4 * g + r;   // C/D layout: row = 4*(lane>>4)+reg, col = lane&15
    si_[r] = sigS[mm];
    so_[r] = sigS[NN + mm];
    sl_[r] = sigS[2 * NN + mm];
  }

  const floatx4 zz = {0.f, 0.f, 0.f, 0.f};
  #pragma unroll
  for (int pass = 0; pass < 2; ++pass){
    const int dbase = 128 * pass;
    floatx4 acc1[8], acc2[8];
    #pragma unroll
    for (int i = 0; i < 8; ++i){ acc1[i] = zz; acc2[i] = zz; }

    #pragma unroll
    for (int k0 = 0; k0 < 128; k0 += 32){
      const int kk = k0 + 8 * g;
      short8v a1 = *(const short8v*)&Abf[ mrow        * 128 + kk];
      short8v a2 = *(const short8v*)&Abf[(128 + mrow) * 128 + kk];
      #pragma unroll
      for (int df = 0; df < 8; ++df){
        int d = dbase + 16 * df + m16;
        const short8v bv = *(const short8v*)&Ht[d * NN + (kk ^ ((d & 7) << 3))];
        acc1[df] = __builtin_amdgcn_mfma_f32_16x16x32_bf16(a1, bv, acc1[df], 0, 0, 0);
        acc2[df] = __builtin_amdgcn_mfma_f32_16x16x32_bf16(a2, bv, acc2[df], 0, 0, 0);
      }
    }

    // ---- epilogue: out = relu((C1+eb)*sig_in + (C2+oeb)*sig_out + H*sig_loop) ----
    #pragma unroll
    for (int df = 0; df < 8; ++df){
      int d  = dbase + 16 * df + m16;
      int m0 = 16 * wave + 4 * g;
      short4v hv = *(const short4v*)&Ht[d * NN + (m0 ^ ((d & 7) << 3))];  // H[m0..m0+3][d]
      #pragma unroll
      for (int r = 0; r < 4; ++r){
        int mm = m0 + r;
        float hl = bf2f((unsigned short)hv[r]);
        float v = acc1[df][r] * si_[r] + acc2[df][r] * so_[r] + hl * sl_[r]
                + eb [mm * ND + d] * si_[r]
                + oeb[mm * ND + d] * so_[r];
        Ob[mm * ND + d] = fmaxf(v, 0.f);
      }
    }
  }
}

extern "C" void kernel_launch(void* const* d_in, const int* in_sizes, int n_in,
                              void* d_out, int out_size, void* d_ws, size_t ws_size,
                              hipStream_t stream){
  const float* H    = (const float*)d_in[0];
  const float* ain  = (const float*)d_in[1];
  const float* aout = (const float*)d_in[2];
  const float* eb   = (const float*)d_in[3];
  const float* gwp  = (const float*)d_in[4];
  const float* bgp  = (const float*)d_in[5];
  const float* oebp = (const float*)d_in[6];
  const float* ogwp = (const float*)d_in[7];
  const float* obgp = (const float*)d_in[8];
  const float* lwp  = (const float*)d_in[9];
  unsigned short* Abf = (unsigned short*)d_ws;   // 64 KB

  prep_A<<<128, 256, 0, stream>>>(ain, aout, Abf);
  gcn_main<<<4096, 512, 0, stream>>>(H, Abf, eb, gwp, bgp, oebp, ogwp, obgp, lwp,
                                     (float*)d_out);
}